// Round 3
// baseline (1346.911 us; speedup 1.0000x reference)
//
#include <hip/hip_runtime.h>
#include <math.h>

#define DIM      32
#define N_NODES  100000
#define N_EDGES  1600000
#define NENT     (2 * N_EDGES)
#define L0       0.1f
#define BSHIFT   6
#define BNODES   64                                   // nodes per bucket
#define NB       ((N_NODES + BNODES - 1) / BNODES)    // 1563 buckets

// ---------------------------------------------------------------------------
// K1: per-block LDS histogram of bucket degrees -> 400k global int atomics
// ---------------------------------------------------------------------------
__global__ __launch_bounds__(256) void count_kernel(
    const int* __restrict__ edges, int* __restrict__ cnt)
{
    __shared__ int hist[NB];
    for (int b = threadIdx.x; b < NB; b += 256) hist[b] = 0;
    __syncthreads();

    const int gid = blockIdx.x * 256 + threadIdx.x;
    const int n   = gridDim.x * 256;
    for (int e = gid; e < N_EDGES; e += n) {
        const int2 ev = ((const int2*)edges)[e];
        atomicAdd(&hist[ev.x >> BSHIFT], 1);
        atomicAdd(&hist[ev.y >> BSHIFT], 1);
    }
    __syncthreads();
    for (int b = threadIdx.x; b < NB; b += 256) {
        const int c = hist[b];
        if (c) atomicAdd(&cnt[b], c);
    }
}

// ---------------------------------------------------------------------------
// K2: single-block exclusive scan of NB=1563 counts -> offs[NB+1], heads[NB]
// ---------------------------------------------------------------------------
__global__ __launch_bounds__(256) void scan_kernel(
    const int* __restrict__ cnt, int* __restrict__ offs, int* __restrict__ heads)
{
    __shared__ int tsum[256];
    const int t    = threadIdx.x;
    const int base = t * 7;                 // 256*7 = 1792 >= 1563

    int local[7];
    int s = 0;
    #pragma unroll
    for (int k = 0; k < 7; k++) {
        const int idx = base + k;
        const int c   = (idx < NB) ? cnt[idx] : 0;
        local[k] = s;                       // thread-local exclusive prefix
        s += c;
    }
    tsum[t] = s;
    __syncthreads();
    for (int off = 1; off < 256; off <<= 1) {   // Hillis-Steele inclusive
        int v = (t >= off) ? tsum[t - off] : 0;
        __syncthreads();
        if (t >= off) tsum[t] += v;
        __syncthreads();
    }
    const int tbase = (t > 0) ? tsum[t - 1] : 0;
    #pragma unroll
    for (int k = 0; k < 7; k++) {
        const int idx = base + k;
        if (idx < NB) {
            const int o = tbase + local[k];
            offs[idx]  = o;
            heads[idx] = o;
        }
    }
    if (t == 255) offs[NB] = tsum[255];
}

// ---------------------------------------------------------------------------
// K3: fill entries. entry = (other_node << 6) | (target_node & 63).
// Slots come from per-bucket atomic tails -> writes stream into ~1563 hot
// lines (sequential within bucket), not random thrash.
// ---------------------------------------------------------------------------
__global__ __launch_bounds__(256) void fill_kernel(
    const int* __restrict__ edges, int* __restrict__ heads,
    int* __restrict__ entries)
{
    const int gid = blockIdx.x * 256 + threadIdx.x;
    const int n   = gridDim.x * 256;
    for (int e = gid; e < N_EDGES; e += n) {
        const int2 ev = ((const int2*)edges)[e];
        const int u = ev.x, v = ev.y;
        const int su = atomicAdd(&heads[u >> BSHIFT], 1);
        entries[su] = (v << BSHIFT) | (u & (BNODES - 1));
        const int sv = atomicAdd(&heads[v >> BSHIFT], 1);
        entries[sv] = (u << BSHIFT) | (v & (BNODES - 1));
    }
}

// ---------------------------------------------------------------------------
// K4: one block per bucket. x-slice + grad-slice in LDS; per entry: gather
// x[other] (the single 820MB pass), dot+factor in-register, LDS atomicAdd.
// Global grad written once, non-atomically. Energy: 0.25*delta^2 per entry
// (each edge appears at both endpoints -> 0.5*delta^2 total).
// ---------------------------------------------------------------------------
__global__ __launch_bounds__(256) void accumulate_kernel(
    const float* __restrict__ x, const int* __restrict__ offs,
    const int* __restrict__ entries, float* __restrict__ out)
{
    __shared__ float  xs[BNODES * DIM];
    __shared__ float  gs[BNODES * DIM];
    __shared__ double es[4];

    const int tid      = threadIdx.x;
    const int lane     = tid & 63;
    const int d        = lane & 31;
    const int hw       = tid >> 5;          // half-wave id 0..7
    const int b        = blockIdx.x;
    const int nodeBase = b * BNODES;
    float* __restrict__ grad = out + 1;

    for (int k = tid; k < BNODES * DIM; k += 256) {
        const int node = nodeBase + (k >> 5);
        xs[k] = (node < N_NODES) ? x[nodeBase * DIM + k] : 0.0f;
        gs[k] = 0.0f;
    }
    __syncthreads();

    const int   start = offs[b];
    const int   end   = offs[b + 1];
    const float Jd    = (d == 0) ? -1.0f : 1.0f;
    double energy = 0.0;

    for (int i0 = start + hw; i0 < end; i0 += 8 * 4) {
        int ent[4]; float xo[4]; bool act[4];
        #pragma unroll
        for (int k = 0; k < 4; k++) {          // gather phase: 4 rows in flight
            const int idx = i0 + 8 * k;
            act[k] = idx < end;                // uniform across half-wave
            ent[k] = act[k] ? entries[idx] : 0;
            xo[k]  = act[k] ? x[(ent[k] >> BSHIFT) * DIM + d] : 0.0f;
        }
        #pragma unroll
        for (int k = 0; k < 4; k++) {
            if (!act[k]) continue;
            const int   tl = ent[k] & (BNODES - 1);
            const float xt = xs[tl * DIM + d];   // banks 0..31, conflict-free
            float p = xt * xo[k];
            if (d == 0) p = -p;
            #pragma unroll
            for (int off = 16; off; off >>= 1)
                p += __shfl_xor(p, off, 32);

            const float inner = fminf(p, -1.0000001f);
            const float zm1   = -inner - 1.0f;
            const float s     = sqrtf(zm1 * (zm1 + 2.0f));
            const float dist  = log1pf(zm1 + s);
            const float delta = dist - L0;
            const float f     = -delta / (s + 1e-9f);

            atomicAdd(&gs[tl * DIM + d], f * Jd * xo[k]);
            if (d == 0) energy += 0.25 * (double)delta * (double)delta;
        }
    }
    __syncthreads();

    for (int k = tid; k < BNODES * DIM; k += 256) {
        const int node = nodeBase + (k >> 5);
        if (node < N_NODES) grad[nodeBase * DIM + k] = gs[k];
    }

    #pragma unroll
    for (int off = 32; off; off >>= 1)
        energy += __shfl_xor(energy, off, 64);
    if (lane == 0) es[tid >> 6] = energy;
    __syncthreads();
    if (tid == 0)
        atomicAdd(&out[0], (float)(es[0] + es[1] + es[2] + es[3]));
}

// ---------------------------------------------------------------------------
// Fallback (ws too small): R1 fused kernel, known-correct at 505 us.
// ---------------------------------------------------------------------------
__global__ __launch_bounds__(256) void spring_edge_kernel(
    const float* __restrict__ x,
    const int*   __restrict__ edges,
    float*       __restrict__ out)
{
    const int tid    = threadIdx.x;
    const int lane   = tid & 63;
    const int d      = lane & 31;
    const int half   = lane >> 5;
    const int waveId = (blockIdx.x * blockDim.x + tid) >> 6;
    const int nWaves = (gridDim.x * blockDim.x) >> 6;

    float* __restrict__ grad = out + 1;
    const float Jd = (d == 0) ? -1.0f : 1.0f;
    double energy = 0.0;

    for (int e0 = waveId * 2; e0 < N_EDGES; e0 += nWaves * 2) {
        const int  e      = e0 + half;
        const bool active = (e < N_EDGES);
        int u = 0, v = 0;
        float xu = 0.0f, xv = 0.0f;
        if (active) {
            u  = edges[2 * e];
            v  = edges[2 * e + 1];
            xu = x[u * DIM + d];
            xv = x[v * DIM + d];
        }
        float p = xu * xv;
        if (d == 0) p = -p;
        #pragma unroll
        for (int off = 16; off; off >>= 1)
            p += __shfl_xor(p, off, 32);

        const float inner  = fminf(p, -1.0000001f);
        const float zm1    = -inner - 1.0f;
        const float s      = sqrtf(zm1 * (zm1 + 2.0f));
        const float dist   = log1pf(zm1 + s);
        const float delta  = dist - L0;
        const float factor = -delta / (s + 1e-9f);

        if (active) {
            atomicAdd(&grad[u * DIM + d], factor * xv * Jd);
            atomicAdd(&grad[v * DIM + d], factor * xu * Jd);
            if (d == 0)
                energy += 0.5 * (double)delta * (double)delta;
        }
    }
    #pragma unroll
    for (int off = 32; off; off >>= 1)
        energy += __shfl_xor(energy, off, 64);
    __shared__ double s_e[4];
    if (lane == 0) s_e[tid >> 6] = energy;
    __syncthreads();
    if (tid == 0)
        atomicAdd(&out[0], (float)(s_e[0] + s_e[1] + s_e[2] + s_e[3]));
}

extern "C" void kernel_launch(void* const* d_in, const int* in_sizes, int n_in,
                              void* d_out, int out_size, void* d_ws, size_t ws_size,
                              hipStream_t stream) {
    const float* x     = (const float*)d_in[0];
    const int*   edges = (const int*)d_in[1];
    float*       out   = (float*)d_out;

    hipMemsetAsync(out, 0, (size_t)out_size * sizeof(float), stream);

    const size_t need = (size_t)(NB + (NB + 1) + NB + NENT) * sizeof(int);
    if (ws_size >= need) {
        int* cnt     = (int*)d_ws;
        int* offs    = cnt + NB;
        int* heads   = offs + (NB + 1);
        int* entries = heads + NB;

        hipMemsetAsync(cnt, 0, (size_t)NB * sizeof(int), stream);
        count_kernel<<<512, 256, 0, stream>>>(edges, cnt);
        scan_kernel<<<1, 256, 0, stream>>>(cnt, offs, heads);
        fill_kernel<<<1024, 256, 0, stream>>>(edges, heads, entries);
        accumulate_kernel<<<NB, 256, 0, stream>>>(x, offs, entries, out);
    } else {
        spring_edge_kernel<<<4096, 256, 0, stream>>>(x, edges, out);
    }
}

// Round 4
// 279.310 us; speedup vs baseline: 4.8223x; 4.8223x over previous
//
#include <hip/hip_runtime.h>
#include <hip/hip_fp16.h>
#include <math.h>

#define DIM      32
#define HDIM     16                // DIM/2 float2 / half2 pairs per row
#define N_NODES  100000
#define N_EDGES  1600000
#define L0       0.1f

// ---------------------------------------------------------------------------
// Fused edge kernel, f16-packed atomics. One QUARTER-wave (16 lanes) per
// edge; lane k owns dims (2k, 2k+1) as float2.  Per edge: 2x128B coalesced
// row gathers, 4-step shfl reduce (width 16), scalar chain, then ONE
// global_atomic_pk_add_f16 per endpoint row per lane -> 32 atomic dwords
// per edge instead of R1's 64.  Grad accumulates in an f16 workspace.
// ---------------------------------------------------------------------------
__global__ __launch_bounds__(256) void spring_edge_f16_kernel(
    const float*  __restrict__ x,
    const int*    __restrict__ edges,
    __half2*      __restrict__ grad_h,   // N_NODES*HDIM half2
    float*        __restrict__ out)      // out[0] = energy
{
    const int tid   = threadIdx.x;
    const int lane  = tid & 63;
    const int k     = lane & 15;        // float2 pair index 0..15
    const int quad  = lane >> 4;        // which of the wave's 4 edges
    const int qId   = ((blockIdx.x * blockDim.x + tid) >> 6) * 4 + quad;
    const int nQuad = ((gridDim.x * blockDim.x) >> 6) * 4;

    const float2* __restrict__ x2 = (const float2*)x;
    const float Jx = (k == 0) ? -1.0f : 1.0f;   // J on dim0 = lane0 .x

    double energy = 0.0;

    for (int e = qId; e < N_EDGES; e += nQuad) {
        const int2 ev = ((const int2*)edges)[e];   // quarter-wave uniform, L1 broadcast
        const int  u  = ev.x, v = ev.y;

        const float2 xu = x2[u * HDIM + k];        // 16 lanes x 8B = 128B row
        const float2 xv = x2[v * HDIM + k];

        // Minkowski dot: J flips dim0 only (lane 0 .x)
        float p = Jx * xu.x * xv.x + xu.y * xv.y;
        #pragma unroll
        for (int off = 8; off; off >>= 1)
            p += __shfl_xor(p, off, 16);

        const float inner = fminf(p, -1.0000001f);
        const float zm1   = -inner - 1.0f;               // z-1 >= 1e-7
        const float s     = sqrtf(zm1 * (zm1 + 2.0f));   // sqrt(z^2-1)
        const float dist  = log1pf(zm1 + s);             // acosh(z)
        const float delta = dist - L0;
        const float f     = -delta / (s + 1e-9f);        // K = 1

        // grad[u] += f * (xv*J) ; grad[v] += f * (xu*J)  -- packed f16 atomics
        unsafeAtomicAdd(&grad_h[u * HDIM + k],
                        __floats2half2_rn(f * Jx * xv.x, f * xv.y));
        unsafeAtomicAdd(&grad_h[v * HDIM + k],
                        __floats2half2_rn(f * Jx * xu.x, f * xu.y));

        if (k == 0)
            energy += 0.5 * (double)delta * (double)delta;
    }

    // lanes 0,16,32,48 hold energy; butterfly over full wave then block reduce
    #pragma unroll
    for (int off = 32; off; off >>= 1)
        energy += __shfl_xor(energy, off, 64);

    __shared__ double s_e[4];
    if (lane == 0) s_e[tid >> 6] = energy;
    __syncthreads();
    if (tid == 0)
        atomicAdd(&out[0], (float)(s_e[0] + s_e[1] + s_e[2] + s_e[3]));
}

// ---------------------------------------------------------------------------
// f16 workspace -> f32 grad.  out+1 is only 4B-aligned, so scalar stores.
// ---------------------------------------------------------------------------
__global__ __launch_bounds__(256) void convert_kernel(
    const __half2* __restrict__ grad_h, float* __restrict__ grad)
{
    const int i = blockIdx.x * 256 + threadIdx.x;     // over N_NODES*HDIM
    if (i < N_NODES * HDIM) {
        const float2 f = __half22float2(grad_h[i]);
        grad[2 * i]     = f.x;
        grad[2 * i + 1] = f.y;
    }
}

// ---------------------------------------------------------------------------
// Fallback (ws too small): R1 fused kernel, known-correct at 505 us.
// ---------------------------------------------------------------------------
__global__ __launch_bounds__(256) void spring_edge_kernel(
    const float* __restrict__ x,
    const int*   __restrict__ edges,
    float*       __restrict__ out)
{
    const int tid    = threadIdx.x;
    const int lane   = tid & 63;
    const int d      = lane & 31;
    const int half   = lane >> 5;
    const int waveId = (blockIdx.x * blockDim.x + tid) >> 6;
    const int nWaves = (gridDim.x * blockDim.x) >> 6;

    float* __restrict__ grad = out + 1;
    const float Jd = (d == 0) ? -1.0f : 1.0f;
    double energy = 0.0;

    for (int e0 = waveId * 2; e0 < N_EDGES; e0 += nWaves * 2) {
        const int  e      = e0 + half;
        const bool active = (e < N_EDGES);
        int u = 0, v = 0;
        float xu = 0.0f, xv = 0.0f;
        if (active) {
            u  = edges[2 * e];
            v  = edges[2 * e + 1];
            xu = x[u * DIM + d];
            xv = x[v * DIM + d];
        }
        float p = xu * xv;
        if (d == 0) p = -p;
        #pragma unroll
        for (int off = 16; off; off >>= 1)
            p += __shfl_xor(p, off, 32);

        const float inner  = fminf(p, -1.0000001f);
        const float zm1    = -inner - 1.0f;
        const float s      = sqrtf(zm1 * (zm1 + 2.0f));
        const float dist   = log1pf(zm1 + s);
        const float delta  = dist - L0;
        const float factor = -delta / (s + 1e-9f);

        if (active) {
            atomicAdd(&grad[u * DIM + d], factor * xv * Jd);
            atomicAdd(&grad[v * DIM + d], factor * xu * Jd);
            if (d == 0)
                energy += 0.5 * (double)delta * (double)delta;
        }
    }
    #pragma unroll
    for (int off = 32; off; off >>= 1)
        energy += __shfl_xor(energy, off, 64);
    __shared__ double s_e[4];
    if (lane == 0) s_e[tid >> 6] = energy;
    __syncthreads();
    if (tid == 0)
        atomicAdd(&out[0], (float)(s_e[0] + s_e[1] + s_e[2] + s_e[3]));
}

extern "C" void kernel_launch(void* const* d_in, const int* in_sizes, int n_in,
                              void* d_out, int out_size, void* d_ws, size_t ws_size,
                              hipStream_t stream) {
    const float* x     = (const float*)d_in[0];
    const int*   edges = (const int*)d_in[1];
    float*       out   = (float*)d_out;

    const size_t need = (size_t)N_NODES * HDIM * sizeof(__half2);   // 6.4 MB
    if (ws_size >= need) {
        __half2* grad_h = (__half2*)d_ws;
        hipMemsetAsync(out, 0, sizeof(float), stream);     // energy slot only
        hipMemsetAsync(grad_h, 0, need, stream);
        spring_edge_f16_kernel<<<4096, 256, 0, stream>>>(x, edges, grad_h, out);
        convert_kernel<<<(N_NODES * HDIM + 255) / 256, 256, 0, stream>>>(
            grad_h, out + 1);
    } else {
        hipMemsetAsync(out, 0, (size_t)out_size * sizeof(float), stream);
        spring_edge_kernel<<<4096, 256, 0, stream>>>(x, edges, out);
    }
}

// Round 5
// 274.152 us; speedup vs baseline: 4.9130x; 1.0188x over previous
//
#include <hip/hip_runtime.h>
#include <hip/hip_fp16.h>
#include <math.h>

#define DIM      32
#define HDIM     16                // DIM/2 float2 / half2 pairs per row
#define N_NODES  100000
#define N_EDGES  1600000
#define L0       0.1f

// ---------------------------------------------------------------------------
// Fused edge kernel, f16-packed atomics, 2-edge software pipeline.
// One QUARTER-wave (16 lanes) per edge; lane k owns dims (2k, 2k+1).
// Per iteration: 2 edges' loads issued back-to-back (2 edge int2 + 4 row
// float2 gathers in flight), then two independent compute chains, then
// 4 pk-f16 atomics. 32 atomic dwords per edge = the measured floor
// (memory-side atomic path ~1 TB/s write, 1 sector per row-touch).
// Energy accumulates into a ws slot so d_out needs no memset.
// ---------------------------------------------------------------------------
__global__ __launch_bounds__(256) void spring_edge_f16_kernel(
    const float*  __restrict__ x,
    const int*    __restrict__ edges,
    __half2*      __restrict__ grad_h,     // N_NODES*HDIM half2 (ws)
    float*        __restrict__ energy_ws)  // 1 float (ws, pre-zeroed)
{
    const int tid   = threadIdx.x;
    const int lane  = tid & 63;
    const int k     = lane & 15;        // float2 pair index 0..15
    const int quad  = lane >> 4;        // which of the wave's 4 edges
    const int qId   = ((blockIdx.x * blockDim.x + tid) >> 6) * 4 + quad;
    const int nQuad = ((gridDim.x * blockDim.x) >> 6) * 4;

    const float2* __restrict__ x2 = (const float2*)x;
    const float Jx = (k == 0) ? -1.0f : 1.0f;   // J on dim0 = lane0 .x

    double energy = 0.0;

    for (int e0 = qId; e0 < N_EDGES; e0 += 2 * nQuad) {
        const int  e1 = e0 + nQuad;
        const bool a1 = (e1 < N_EDGES);

        // ---- issue all loads for both edges up front (6 vmem ops) ----
        const int2 ev0 = ((const int2*)edges)[e0];
        const int2 ev1 = a1 ? ((const int2*)edges)[e1] : make_int2(0, 0);
        const float2 xu0 = x2[ev0.x * HDIM + k];    // 16 lanes x 8B = 128B row
        const float2 xv0 = x2[ev0.y * HDIM + k];
        const float2 xu1 = x2[ev1.x * HDIM + k];
        const float2 xv1 = x2[ev1.y * HDIM + k];

        // ---- two independent dot-product reduces (interleaved) ----
        float p0 = Jx * xu0.x * xv0.x + xu0.y * xv0.y;
        float p1 = Jx * xu1.x * xv1.x + xu1.y * xv1.y;
        #pragma unroll
        for (int off = 8; off; off >>= 1) {
            p0 += __shfl_xor(p0, off, 16);
            p1 += __shfl_xor(p1, off, 16);
        }

        // ---- chain 0 ----
        {
            const float inner = fminf(p0, -1.0000001f);
            const float zm1   = -inner - 1.0f;
            const float s     = sqrtf(zm1 * (zm1 + 2.0f));
            const float dist  = log1pf(zm1 + s);
            const float delta = dist - L0;
            const float f     = -delta / (s + 1e-9f);
            unsafeAtomicAdd(&grad_h[ev0.x * HDIM + k],
                            __floats2half2_rn(f * Jx * xv0.x, f * xv0.y));
            unsafeAtomicAdd(&grad_h[ev0.y * HDIM + k],
                            __floats2half2_rn(f * Jx * xu0.x, f * xu0.y));
            if (k == 0) energy += 0.5 * (double)delta * (double)delta;
        }
        // ---- chain 1 ----
        if (a1) {
            const float inner = fminf(p1, -1.0000001f);
            const float zm1   = -inner - 1.0f;
            const float s     = sqrtf(zm1 * (zm1 + 2.0f));
            const float dist  = log1pf(zm1 + s);
            const float delta = dist - L0;
            const float f     = -delta / (s + 1e-9f);
            unsafeAtomicAdd(&grad_h[ev1.x * HDIM + k],
                            __floats2half2_rn(f * Jx * xv1.x, f * xv1.y));
            unsafeAtomicAdd(&grad_h[ev1.y * HDIM + k],
                            __floats2half2_rn(f * Jx * xu1.x, f * xu1.y));
            if (k == 0) energy += 0.5 * (double)delta * (double)delta;
        }
    }

    // lanes 0,16,32,48 hold energy; butterfly over full wave, block reduce
    #pragma unroll
    for (int off = 32; off; off >>= 1)
        energy += __shfl_xor(energy, off, 64);

    __shared__ double s_e[4];
    if (lane == 0) s_e[tid >> 6] = energy;
    __syncthreads();
    if (tid == 0)
        atomicAdd(energy_ws, (float)(s_e[0] + s_e[1] + s_e[2] + s_e[3]));
}

// ---------------------------------------------------------------------------
// f16 ws -> f32 grad, plus energy ws -> out[0].  Writes every element of
// d_out, so no d_out memset is needed anywhere.
// ---------------------------------------------------------------------------
__global__ __launch_bounds__(256) void convert_kernel(
    const __half2* __restrict__ grad_h,
    const float*   __restrict__ energy_ws,
    float*         __restrict__ out)
{
    const int i = blockIdx.x * 256 + threadIdx.x;     // over N_NODES*HDIM
    if (i < N_NODES * HDIM) {
        const float2 f = __half22float2(grad_h[i]);
        out[1 + 2 * i]     = f.x;
        out[1 + 2 * i + 1] = f.y;
    }
    if (i == 0) out[0] = *energy_ws;
}

// ---------------------------------------------------------------------------
// Fallback (ws too small): R1 fused kernel, known-correct at 505 us.
// ---------------------------------------------------------------------------
__global__ __launch_bounds__(256) void spring_edge_kernel(
    const float* __restrict__ x,
    const int*   __restrict__ edges,
    float*       __restrict__ out)
{
    const int tid    = threadIdx.x;
    const int lane   = tid & 63;
    const int d      = lane & 31;
    const int half   = lane >> 5;
    const int waveId = (blockIdx.x * blockDim.x + tid) >> 6;
    const int nWaves = (gridDim.x * blockDim.x) >> 6;

    float* __restrict__ grad = out + 1;
    const float Jd = (d == 0) ? -1.0f : 1.0f;
    double energy = 0.0;

    for (int e0 = waveId * 2; e0 < N_EDGES; e0 += nWaves * 2) {
        const int  e      = e0 + half;
        const bool active = (e < N_EDGES);
        int u = 0, v = 0;
        float xu = 0.0f, xv = 0.0f;
        if (active) {
            u  = edges[2 * e];
            v  = edges[2 * e + 1];
            xu = x[u * DIM + d];
            xv = x[v * DIM + d];
        }
        float p = xu * xv;
        if (d == 0) p = -p;
        #pragma unroll
        for (int off = 16; off; off >>= 1)
            p += __shfl_xor(p, off, 32);

        const float inner  = fminf(p, -1.0000001f);
        const float zm1    = -inner - 1.0f;
        const float s      = sqrtf(zm1 * (zm1 + 2.0f));
        const float dist   = log1pf(zm1 + s);
        const float delta  = dist - L0;
        const float factor = -delta / (s + 1e-9f);

        if (active) {
            atomicAdd(&grad[u * DIM + d], factor * xv * Jd);
            atomicAdd(&grad[v * DIM + d], factor * xu * Jd);
            if (d == 0)
                energy += 0.5 * (double)delta * (double)delta;
        }
    }
    #pragma unroll
    for (int off = 32; off; off >>= 1)
        energy += __shfl_xor(energy, off, 64);
    __shared__ double s_e[4];
    if (lane == 0) s_e[tid >> 6] = energy;
    __syncthreads();
    if (tid == 0)
        atomicAdd(&out[0], (float)(s_e[0] + s_e[1] + s_e[2] + s_e[3]));
}

extern "C" void kernel_launch(void* const* d_in, const int* in_sizes, int n_in,
                              void* d_out, int out_size, void* d_ws, size_t ws_size,
                              hipStream_t stream) {
    const float* x     = (const float*)d_in[0];
    const int*   edges = (const int*)d_in[1];
    float*       out   = (float*)d_out;

    const size_t grad_bytes = (size_t)N_NODES * HDIM * sizeof(__half2); // 6.4 MB
    const size_t need       = grad_bytes + sizeof(float);               // + energy

    if (ws_size >= need) {
        __half2* grad_h    = (__half2*)d_ws;
        float*   energy_ws = (float*)((char*)d_ws + grad_bytes);

        hipMemsetAsync(d_ws, 0, need, stream);   // grad ws + energy slot
        spring_edge_f16_kernel<<<4096, 256, 0, stream>>>(x, edges, grad_h,
                                                         energy_ws);
        convert_kernel<<<(N_NODES * HDIM + 255) / 256, 256, 0, stream>>>(
            grad_h, energy_ws, out);
    } else {
        hipMemsetAsync(out, 0, (size_t)out_size * sizeof(float), stream);
        spring_edge_kernel<<<4096, 256, 0, stream>>>(x, edges, out);
    }
}